// Round 17
// baseline (32987.140 us; speedup 1.0000x reference)
//
#include <hip/hip_runtime.h>
#include <hip/hip_bf16.h>

// Zero-exchange decoder, fp8 gates GEMM. 128 blocks x 512 thr; block owns 16
// batch rows for ALL 256 steps; h/x/ctx (bf16 + fp8 image), c, parts in LDS.
// NO data barriers (R13 structure, correctness-proven). R13 failed on Wbig L2
// misses (2.36MB bf16 stream, 70% hit -> 90MB/step HBM). Fix: Wbig in fp8-e4m3
// (1.18MB/XCD << 4MB L2 -> unconditionally resident). Gates GEMM uses
// mfma_f32_16x16x32_fp8_fp8 (A from fp8 LDS image); uh/attention/head/cell
// stay bf16/f32 so the softmax/alpha path is numerically unchanged.
// Per-step fence-free cohort resync (bk&7 = XCD under round-robin) for pacing.

#include <hip/hip_fp8.h>

typedef __attribute__((ext_vector_type(8))) short short8;
typedef __attribute__((ext_vector_type(4))) float floatx4;

#define DEV static __device__ __forceinline__
#define C2LE 2.885390082f    // 2*log2(e)
#define LOG2E 1.4426950409f
#define LN2 0.6931471806f

DEV unsigned short f2bf(float f) {
    unsigned int u = __float_as_uint(f);
    unsigned int r = (u + 0x7FFFu + ((u >> 16) & 1u)) >> 16;
    return (unsigned short)r;
}
DEV float bf2f(unsigned short u) { return __uint_as_float(((unsigned int)u) << 16); }
DEV float rcp_f(float x) { float r; asm("v_rcp_f32 %0, %1" : "=v"(r) : "v"(x)); return r; }
DEV float tanh_f(float x) { return 1.f - 2.f * rcp_f(1.f + exp2f(x * C2LE)); }
DEV float sigm(float x) { return rcp_f(1.f + exp2f(-x * LOG2E)); }

// float -> fp8 e4m3fn (RNE, saturating). Manual to avoid header variance.
DEV unsigned char f2fp8(float f) {
    unsigned int bits = __float_as_uint(f);
    unsigned char s = (unsigned char)((bits >> 31) << 7);
    float a = fabsf(f);
    if (a > 448.f) a = 448.f;
    if (a == 0.f) return s;
    unsigned int u = __float_as_uint(a);
    int e = (int)((u >> 23) & 0xFF) - 127;
    if (e >= -6) {
        unsigned int m = u & 0x7FFFFF;
        unsigned int keep = m >> 20;
        unsigned int rest = m & 0xFFFFF;
        unsigned int val = ((unsigned int)(e + 7) << 3) | keep;
        if (rest > 0x80000u || (rest == 0x80000u && (keep & 1u))) val++;
        if (val > 126u) val = 126u;   // max normal 448, avoid NaN encoding
        return s | (unsigned char)val;
    } else {
        int q = (int)rintf(a * 512.f);   // subnormal: q * 2^-9 (q<=8 encodes 2^-6)
        return s | (unsigned char)q;
    }
}

DEV void st_flag(int* p, int v) {
    asm volatile("global_store_dword %0, %1, off sc0 sc1" :: "v"(p), "v"(v) : "memory");
}
DEV int ld_flag(const int* p) {
    int v;
    asm volatile("global_load_dword %0, %1, off sc0 sc1\n\ts_waitcnt vmcnt(0)"
                 : "=v"(v) : "v"(p) : "memory");
    return v;
}

// ---------------- workspace layout (bytes) ----------------
#define OFF_H0     ((size_t)0)          // bf16 [2048][512]
#define OFF_C0     ((size_t)2097152)    // f32  [2048][512]
#define OFF_PARTS  ((size_t)6291456)    // bf16 [2048][64][32]
#define OFF_WSMALL ((size_t)17039360)   // bf16 [160][512]: Uw(128), betaw(32)
#define OFF_WW2    ((size_t)17203200)   // bf16 [128][32] = C2LE*Ww
#define OFF_BIAS   ((size_t)17211392)   // f32  [2048] b_ih+b_hh (orig order)
#define OFF_AVG    ((size_t)17219584)   // f32  [2048][64]
#define OFF_FLAGS  ((size_t)17743872)   // int flags[128*32], 128B stride
#define OFF_WBIG8  ((size_t)17760256)   // fp8  [2048][576], perm row p=4j+g <- orig g*512+j

// fence-free cohort resync: 16 blocks sharing an XCD (bk&7 under round-robin).
// No data dependence -> no fences. Lanes 0..15 poll the cohort's 16 flags.
DEV void resync(int* flags, int bk, int step) {
    __syncthreads();
    if (threadIdx.x < 64) {
        if (threadIdx.x == 0) st_flag(flags + bk * 32, step);
        int idx = threadIdx.x * 8 + (bk & 7);
        for (;;) {
            int v = step;
            if (threadIdx.x < 16) v = ld_flag(flags + idx * 32);
            if (__all(v >= step)) break;
        }
    }
    __syncthreads();
}

__global__ void k_init(int* flags) {
    int i = blockIdx.x * 256 + threadIdx.x;
    if (i < 128 * 32) flags[i] = 0;
}

__global__ void k_avg(const float* __restrict__ img, float* __restrict__ avg) {
    int idx = blockIdx.x * 256 + threadIdx.x;
    int b = idx >> 6, p = idx & 63;
    const float* base = img + (size_t)b * 2048 + p;
    float s = 0.f;
#pragma unroll
    for (int k = 0; k < 32; ++k) s += base[k * 64];
    avg[idx] = s * (1.f / 32.f);
}

__global__ void k_prep(const float* __restrict__ Whh, const float* __restrict__ Wih,
                       const float* __restrict__ Uw, const float* __restrict__ betaw,
                       const float* __restrict__ Ww, const float* __restrict__ bih,
                       const float* __restrict__ bhh,
                       unsigned char* __restrict__ Wbig8, unsigned short* __restrict__ Wsmall,
                       unsigned short* __restrict__ Ww2, float* __restrict__ bias_cat) {
    int p = blockIdx.x, tid = threadIdx.x;
    int g = p & 3, j = p >> 2, orig = g * 512 + j;
    for (int k = tid; k < 576; k += 256) {
        float v = 0.f;
        if (k < 512) v = Whh[(size_t)orig * 512 + k];
        else if (k < 556) v = Wih[(size_t)orig * 44 + (k - 512)];
        Wbig8[(size_t)p * 576 + k] = f2fp8(v);
    }
    if (p < 160) {
        for (int k = tid; k < 512; k += 256) {
            float v = (p < 128) ? Uw[(size_t)p * 512 + k] : betaw[(size_t)(p - 128) * 512 + k];
            Wsmall[(size_t)p * 512 + k] = f2bf(v);
        }
    }
    if (p < 128 && tid < 32) Ww2[p * 32 + tid] = f2bf(C2LE * Ww[p * 32 + tid]);
    if (tid == 0) bias_cat[orig] = bih[orig] + bhh[orig];
}

__global__ __launch_bounds__(512) void k_h0c0(const float* __restrict__ avg,
                                              const float* __restrict__ ihw, const float* __restrict__ ihb,
                                              const float* __restrict__ icw, const float* __restrict__ icb,
                                              unsigned short* __restrict__ h0, float* __restrict__ c0) {
    __shared__ float avg_s[8][64];
    int b0 = blockIdx.x * 8, tid = threadIdx.x;
    for (int i = tid; i < 8 * 64; i += 512) avg_s[i >> 6][i & 63] = avg[b0 * 64 + i];
    __syncthreads();
    int j = tid;
    float w0[64];
#pragma unroll
    for (int p4 = 0; p4 < 16; ++p4) {
        float4 v = ((const float4*)(ihw + j * 64))[p4];
        w0[p4 * 4 + 0] = v.x; w0[p4 * 4 + 1] = v.y; w0[p4 * 4 + 2] = v.z; w0[p4 * 4 + 3] = v.w;
    }
    float bh = ihb[j];
#pragma unroll
    for (int bb = 0; bb < 8; ++bb) {
        float s = bh;
#pragma unroll
        for (int p = 0; p < 64; ++p) s += w0[p] * avg_s[bb][p];
        h0[(size_t)(b0 + bb) * 512 + j] = f2bf(tanh_f(s));
    }
#pragma unroll
    for (int p4 = 0; p4 < 16; ++p4) {
        float4 v = ((const float4*)(icw + j * 64))[p4];
        w0[p4 * 4 + 0] = v.x; w0[p4 * 4 + 1] = v.y; w0[p4 * 4 + 2] = v.z; w0[p4 * 4 + 3] = v.w;
    }
    float bc = icb[j];
#pragma unroll
    for (int bb = 0; bb < 8; ++bb) {
        float s = bc;
#pragma unroll
        for (int p = 0; p < 64; ++p) s += w0[p] * avg_s[bb][p];
        c0[(size_t)(b0 + bb) * 512 + j] = tanh_f(s);
    }
}

// parts_bf[b][p][k] = bf16(img[b][k][p])
__global__ __launch_bounds__(256) void k_parts(const float* __restrict__ img,
                                               unsigned short* __restrict__ parts_bf) {
    __shared__ float pl[64][33];
    int b = blockIdx.x, tid = threadIdx.x;
    const float* ib = img + (size_t)b * 2048;
    for (int i = tid; i < 2048; i += 256) pl[i & 63][i >> 6] = ib[i];
    __syncthreads();
    for (int i = tid; i < 2048; i += 256)
        parts_bf[(size_t)b * 2048 + i] = f2bf(pl[i >> 5][i & 31]);
}

__global__ __launch_bounds__(512, 2) void k_scan(
    const unsigned short* __restrict__ h0, const float* __restrict__ c0,
    const unsigned short* __restrict__ parts_bf,
    const unsigned short* __restrict__ Wsmall, const unsigned char* __restrict__ Wbig8,
    const unsigned short* __restrict__ Ww2, const float* __restrict__ bias_cat,
    const float* __restrict__ Ub, const float* __restrict__ betab, const float* __restrict__ Wb,
    const float* __restrict__ vw,
    const float* __restrict__ label, const float* __restrict__ ow, const float* __restrict__ ob,
    float* __restrict__ out_alpha, float* __restrict__ out_logits,
    int* __restrict__ flags)
{
    __shared__ unsigned short xh[16][584];       // 18.7KB h|x|ctx bf16
    __shared__ unsigned char  xh8[16][592];      // 9.3KB  fp8 image (gates A)
    __shared__ unsigned short parts_l[16][2304]; // 73.7KB [p][36] padded
    __shared__ float c_l[16][516];               // 33KB
    __shared__ float uh_l[16][160];              // 10.2KB
    __shared__ float al_l[16][64];               // 4KB
    __shared__ float bias_l[2048];               // 8KB
    __shared__ float vw2_l[128];
    __shared__ float obl[12];

    const int tid = threadIdx.x, w = tid >> 6, lane = tid & 63;
    const int b0 = blockIdx.x * 16;
    const int bk = blockIdx.x;

    // ---- prologue staging (one-time) ----
    for (int i = tid; i < 2048; i += 512) bias_l[i] = bias_cat[i];
    if (tid < 128) vw2_l[tid] = -2.f * vw[tid];
    if (tid < 12) obl[tid] = ob[tid];
    for (int i = tid; i < 16 * 64; i += 512) {
        int row = i >> 6, p = i & 63;
        const short8* src = (const short8*)(parts_bf + (size_t)(b0 + row) * 2048 + p * 32);
        short8* dst = (short8*)&parts_l[row][p * 36];
        dst[0] = src[0]; dst[1] = src[1]; dst[2] = src[2]; dst[3] = src[3];
    }
    for (int i = tid; i < 16 * 64; i += 512) {
        int row = i >> 6, c8 = (i & 63) * 8;
        *(short8*)&xh[row][c8] = *(const short8*)(h0 + (size_t)(b0 + row) * 512 + c8);
    }
    for (int i = tid; i < 16 * 72; i += 512) {
        int row = i / 72, cc = 512 + (i % 72);
        xh[row][cc] = 0;
    }
    for (int i = tid; i < 16 * 80; i += 512) {
        int row = i / 80, cc = 512 + (i % 80);
        xh8[row][cc] = 0;
    }
    for (int i = tid; i < 16 * 512; i += 512) {
        int row = i >> 9, j = i & 511;
        c_l[row][j] = c0[(size_t)(b0 + row) * 512 + j];
    }
    __syncthreads();
    // fp8 image of h(0)
    for (int i = tid; i < 16 * 512; i += 512) {
        int row = i >> 9, col = i & 511;
        xh8[row][col] = f2fp8(bf2f(xh[row][col]));
    }
    float vwsum = 0.f;
#pragma unroll
    for (int d = 0; d < 128; ++d) vwsum += vw2_l[d];
    vwsum *= -0.5f;
    __syncthreads();

    // ---- Uh GEMM: uh_l[16][160] = h @ Wsmall^T (+bias/scale), bf16 ----
    auto do_uh = [&]() {
        for (int nt = w; nt < 10; nt += 8) {
            const unsigned short* Bp = Wsmall + (size_t)(nt * 16 + (lane & 15)) * 512 + (lane >> 4) * 8;
            floatx4 u = {};
#pragma unroll
            for (int k0 = 0; k0 < 512; k0 += 32) {
                short8 a = *(const short8*)&xh[lane & 15][k0 + (lane >> 4) * 8];
                u = __builtin_amdgcn_mfma_f32_16x16x32_bf16(a, *(const short8*)(Bp + k0), u, 0, 0, 0);
            }
            int n = nt * 16 + (lane & 15), r0 = (lane >> 4) * 4;
            float addv = (n < 128) ? (Ub[n] + Wb[n]) : betab[n - 128];
            float scl = (n < 128) ? C2LE : 1.f;
#pragma unroll
            for (int r = 0; r < 4; ++r) uh_l[r0 + r][n] = (u[r] + addv) * scl;
        }
    };

    // ---- attention for step tt (bf16 path, unchanged math) ----
    auto do_attn = [&](int tt) {
#pragma unroll
        for (int u = 0; u < 2; ++u) {
            int row = w * 2 + u, b = b0 + row;
            short8 pa[4];
#pragma unroll
            for (int mt = 0; mt < 4; ++mt)
                pa[mt] = *(const short8*)&parts_l[row][(mt * 16 + (lane & 15)) * 36 + (lane >> 4) * 8];
            float sc[4][4] = {};
#pragma unroll
            for (int nt = 0; nt < 8; ++nt) {
                short8 wwf = *(const short8*)(Ww2 + (size_t)(nt * 16 + (lane & 15)) * 32 + (lane >> 4) * 8);
                int d = nt * 16 + (lane & 15);
                float ud = uh_l[row][d];
                float v2 = vw2_l[d];
#pragma unroll
                for (int mt = 0; mt < 4; ++mt) {
                    floatx4 z = {};
                    floatx4 wsa = __builtin_amdgcn_mfma_f32_16x16x32_bf16(pa[mt], wwf, z, 0, 0, 0);
#pragma unroll
                    for (int r = 0; r < 4; ++r)
                        sc[mt][r] += v2 * rcp_f(1.f + exp2f(wsa[r] + ud));
                }
            }
            float mx = -1e30f;
#pragma unroll
            for (int mt = 0; mt < 4; ++mt)
#pragma unroll
                for (int r = 0; r < 4; ++r) {
                    float s = sc[mt][r];
                    s += __shfl_xor(s, 1); s += __shfl_xor(s, 2);
                    s += __shfl_xor(s, 4); s += __shfl_xor(s, 8);
                    s += vwsum;
                    sc[mt][r] = s;
                    mx = fmaxf(mx, s);
                }
            mx = fmaxf(mx, __shfl_xor(mx, 16));
            mx = fmaxf(mx, __shfl_xor(mx, 32));
            float ssum = 0.f;
            float av[4][4];
#pragma unroll
            for (int mt = 0; mt < 4; ++mt)
#pragma unroll
                for (int r = 0; r < 4; ++r) {
                    av[mt][r] = exp2f((sc[mt][r] - mx) * LOG2E);
                    ssum += av[mt][r];
                }
            ssum += __shfl_xor(ssum, 16);
            ssum += __shfl_xor(ssum, 32);
            float rs = rcp_f(ssum);
#pragma unroll
            for (int mt = 0; mt < 4; ++mt) {
                if ((lane & 15) == mt) {
                    float4 fv = make_float4(av[mt][0] * rs, av[mt][1] * rs, av[mt][2] * rs, av[mt][3] * rs);
                    int p0 = mt * 16 + (lane >> 4) * 4;
                    *(float4*)&out_alpha[((size_t)tt * 2048 + b) * 64 + p0] = fv;
                    *(float4*)&al_l[row][p0] = fv;
                }
            }
            int k = lane & 31, half = lane >> 5;
            float cp = 0.f;
#pragma unroll
            for (int p = 0; p < 32; ++p) {
                int pp = half * 32 + p;
                cp += al_l[row][pp] * bf2f(parts_l[row][pp * 36 + k]);
            }
            cp += __shfl_xor(cp, 32);
            if (half == 0) {
                float cv = cp * sigm(uh_l[row][128 + k]);
                float cq = bf2f(f2bf(cv));     // match bf16 rounding of reference path
                xh[row][524 + k] = f2bf(cv);
                xh8[row][524 + k] = f2fp8(cq);
            }
            if (lane < 12) {
                float xv = label[((size_t)b * 256 + tt) * 12 + lane];
                float xq = bf2f(f2bf(xv));
                xh[row][512 + lane] = f2bf(xv);
                xh8[row][512 + lane] = f2fp8(xq);
            }
        }
    };

    do_uh();
    __syncthreads();
    do_attn(0);
    __syncthreads();

    int rs = 0;
    resync(flags, bk, ++rs);   // align cohort start

    for (int t = 0; t < 256; ++t) {
        // ---- preload fp8 A-frags (regs) so cell can write xh8 in-place ----
        unsigned long long a8[18];
#pragma unroll
        for (int k = 0; k < 18; ++k)
            a8[k] = *(const unsigned long long*)&xh8[lane & 15][k * 32 + (lane >> 4) * 8];
        __syncthreads();   // S1

        // ---- gates GEMM fp8 (wave owns perm p in [w*256,+256)) + fused cell ----
#pragma unroll
        for (int ng = 0; ng < 4; ++ng) {
            const unsigned char* bp = Wbig8 + (size_t)(w * 256 + ng * 64 + (lane & 15)) * 576 + (lane >> 4) * 8;
            unsigned long long br[3][4];
            floatx4 acc[4] = {};
#pragma unroll
            for (int kk = 0; kk < 2; ++kk)
#pragma unroll
                for (int q = 0; q < 4; ++q)
                    br[kk][q] = *(const unsigned long long*)(bp + (size_t)q * 9216 + kk * 32);
#pragma unroll
            for (int k = 0; k < 18; ++k) {
                if (k < 16) {
#pragma unroll
                    for (int q = 0; q < 4; ++q)
                        br[(k + 2) % 3][q] = *(const unsigned long long*)(bp + (size_t)q * 9216 + (k + 2) * 32);
                }
#pragma unroll
                for (int q = 0; q < 4; ++q)
                    acc[q] = __builtin_amdgcn_mfma_f32_16x16x32_fp8_fp8(
                        (long long)a8[k], (long long)br[k % 3][q], acc[q], 0, 0, 0);
            }
            int base = (lane & 48) | (4 * (lane & 3));
            int jl = lane & 3;
#pragma unroll
            for (int q = 0; q < 4; ++q) {
                int j = w * 64 + (ng * 4 + q) * 4 + jl;
                float bi = bias_l[j], bfv = bias_l[512 + j], bg = bias_l[1024 + j], bo = bias_l[1536 + j];
#pragma unroll
                for (int r = 0; r < 4; ++r) {
                    float x = acc[q][r];
                    float g0 = __shfl(x, base + 0);
                    float g1 = __shfl(x, base + 1);
                    float g2 = __shfl(x, base + 2);
                    float g3 = __shfl(x, base + 3);
                    int row = (lane >> 4) * 4 + r;
                    float cold = c_l[row][j];
                    float c2 = sigm(g1 + bfv) * cold + sigm(g0 + bi) * tanh_f(g2 + bg);
                    float h2 = sigm(g3 + bo) * tanh_f(c2);
                    if (((lane >> 2) & 3) == 0) {
                        c_l[row][j] = c2;
                        unsigned short hb = f2bf(h2);
                        xh[row][j] = hb;
                        xh8[row][j] = f2fp8(bf2f(hb));
                    }
                }
            }
        }
        __syncthreads();   // S2: h(t+1) complete (bf16 + fp8)

        // ---- output head: logits[t] from h(t+1); ow from L2-resident global ----
#pragma unroll
        for (int u = 0; u < 2; ++u) {
            int row = w * 2 + u, b = b0 + row;
            short8 hv = *(const short8*)&xh[row][lane * 8];
            float hf[8];
#pragma unroll
            for (int j = 0; j < 8; ++j) hf[j] = bf2f((unsigned short)hv[j]);
            float ov[12];
#pragma unroll
            for (int v = 0; v < 12; ++v) {
                const float* owr = ow + v * 512 + lane * 8;
                float4 o0 = *(const float4*)owr;
                float4 o1 = *(const float4*)(owr + 4);
                float p = hf[0] * o0.x + hf[1] * o0.y + hf[2] * o0.z + hf[3] * o0.w
                        + hf[4] * o1.x + hf[5] * o1.y + hf[6] * o1.z + hf[7] * o1.w;
#pragma unroll
                for (int o = 32; o; o >>= 1) p += __shfl_xor(p, o);
                ov[v] = p + obl[v];
            }
            float mx = ov[0];
#pragma unroll
            for (int v = 1; v < 12; ++v) mx = fmaxf(mx, ov[v]);
            float ss = 0.f;
#pragma unroll
            for (int v = 0; v < 12; ++v) ss += exp2f((ov[v] - mx) * LOG2E);
            float lse = mx + log2f(ss) * LN2;
#pragma unroll
            for (int v = 0; v < 12; ++v)
                if (lane == v) out_logits[((size_t)b * 256 + t) * 12 + v] = ov[v] - lse;
        }
        if (t < 255) do_uh();
        __syncthreads();   // S3: uh_l complete
        if (t < 255) do_attn(t + 1);
        __syncthreads();   // S4: x/ctx complete before next preload

        // ---- per-step cohort pacing (fence-free, no data dependence) ----
        if (t < 255) resync(flags, bk, ++rs);
    }
}

extern "C" void kernel_launch(void* const* d_in, const int* in_sizes, int n_in,
                              void* d_out, int out_size, void* d_ws, size_t ws_size,
                              hipStream_t stream) {
    const float* img   = (const float*)d_in[0];
    const float* label = (const float*)d_in[1];
    const float* Ww    = (const float*)d_in[2];
    const float* Wb    = (const float*)d_in[3];
    const float* Uw    = (const float*)d_in[4];
    const float* Ub    = (const float*)d_in[5];
    const float* vw    = (const float*)d_in[6];
    // d_in[7] = vb (cancels in softmax)
    const float* betaw = (const float*)d_in[8];
    const float* betab = (const float*)d_in[9];
    const float* ihw   = (const float*)d_in[10];
    const float* ihb   = (const float*)d_in[11];
    const float* icw   = (const float*)d_in[12];
    const float* icb   = (const float*)d_in[13];
    const float* Wih   = (const float*)d_in[14];
    const float* Whh   = (const float*)d_in[15];
    const float* bih   = (const float*)d_in[16];
    const float* bhh   = (const float*)d_in[17];
    const float* ow    = (const float*)d_in[18];
    const float* ob    = (const float*)d_in[19];

    char* ws = (char*)d_ws;
    unsigned short* h0       = (unsigned short*)(ws + OFF_H0);
    float*          c0       = (float*)(ws + OFF_C0);
    unsigned short* parts_bf = (unsigned short*)(ws + OFF_PARTS);
    unsigned short* Wsmall   = (unsigned short*)(ws + OFF_WSMALL);
    unsigned short* Ww2      = (unsigned short*)(ws + OFF_WW2);
    float*          bias     = (float*)(ws + OFF_BIAS);
    float*          avg      = (float*)(ws + OFF_AVG);
    int*            flags    = (int*)(ws + OFF_FLAGS);
    unsigned char*  Wbig8    = (unsigned char*)(ws + OFF_WBIG8);

    float* out_logits = (float*)d_out;
    float* out_alpha  = out_logits + (size_t)2048 * 256 * 12;

    k_init<<<16, 256, 0, stream>>>(flags);
    k_avg<<<512, 256, 0, stream>>>(img, avg);
    k_prep<<<2048, 256, 0, stream>>>(Whh, Wih, Uw, betaw, Ww, bih, bhh, Wbig8, Wsmall, Ww2, bias);
    k_h0c0<<<256, 512, 0, stream>>>(avg, ihw, ihb, icw, icb, h0, c0);
    k_parts<<<2048, 256, 0, stream>>>(img, parts_bf);

    k_scan<<<128, 512, 0, stream>>>(h0, c0, parts_bf, Wsmall, Wbig8, Ww2, bias,
                                    Ub, betab, Wb, vw, label, ow, ob,
                                    out_alpha, out_logits, flags);
}